// Round 2
// baseline (1484.151 us; speedup 1.0000x reference)
//
#include <hip/hip_runtime.h>
#include <hip/hip_fp16.h>
#include <cmath>

#define NN 20000
#define EE 500000
#define GG 64
#define TS 8192
#define EPS 1e-5f

__device__ __forceinline__ float softplus_ref(float x) {
    return fmaxf(x, 0.f) + log1pf(__expf(-fabsf(x)));
}
__device__ __forceinline__ float softplus_fast(float x) {
    return fmaxf(x, 0.f) + __logf(1.0f + __expf(-fabsf(x)));
}
__device__ __forceinline__ float sigmoid_fast(float x) {
    return __builtin_amdgcn_rcpf(1.0f + __expf(-x));
}
__device__ __forceinline__ float2 h2f(float w) {
    return __half22float2(*(const __half2*)&w);
}

// gaussian table: g[s][k] = exp(coeff*(d_s - o_k)^2)
__global__ void k_gtab(float* __restrict__ g) {
    int i = blockIdx.x * 256 + threadIdx.x;
    if (i >= TS * 100) return;
    int s = i / 100, k = i - 100 * s;
    float d = s * (6.0f / (TS - 1.0f));
    float o = k * (6.0f / 99.0f);
    float step = 6.0f / 99.0f;
    float coeff = -0.5f / (step * step);
    float df = d - o;
    g[i] = __expf(coeff * df * df);
}

// Nearest-neighbor table, paired channels: Tn[l][s][t] = half2(T[c=t], T[c=t+64])
__global__ void __launch_bounds__(256) k_build_T(
    const float* __restrict__ g, const float* __restrict__ convW,
    const float* __restrict__ convB, __half2* __restrict__ Tn) {
    int lane = threadIdx.x & 63;
    int wv = __builtin_amdgcn_readfirstlane(threadIdx.x >> 6);
    int l = blockIdx.y;
    int s0 = blockIdx.x * 16 + wv * 4;
    const float* w = convW + ((size_t)l * 228 + 128) * 128;
    const float* g0 = g + (size_t)s0 * 100;
    float b0 = convB[l * 128 + lane], b1 = convB[l * 128 + lane + 64];
    float2 a0 = {b0, b1}, a1 = {b0, b1}, a2 = {b0, b1}, a3 = {b0, b1};
#pragma unroll 4
    for (int k = 0; k < 100; k++) {
        float w0 = w[k * 128 + lane];
        float w1 = w[k * 128 + lane + 64];
        float ga = g0[k], gb = g0[100 + k], gc = g0[200 + k], gd = g0[300 + k];
        a0.x += ga * w0; a0.y += ga * w1;
        a1.x += gb * w0; a1.y += gb * w1;
        a2.x += gc * w0; a2.y += gc * w1;
        a3.x += gd * w0; a3.y += gd * w1;
    }
    Tn[((size_t)l * TS + s0 + 0) * 64 + lane] = __floats2half2_rn(a0.x, a0.y);
    Tn[((size_t)l * TS + s0 + 1) * 64 + lane] = __floats2half2_rn(a1.x, a1.y);
    Tn[((size_t)l * TS + s0 + 2) * 64 + lane] = __floats2half2_rn(a2.x, a2.y);
    Tn[((size_t)l * TS + s0 + 3) * 64 + lane] = __floats2half2_rn(a3.x, a3.y);
}

// Wp[l][k][lane] = (W1[k,lane], W1[k,lane+64], W2[k,lane], W2[k,lane+64])
__global__ void k_prepW(const float* __restrict__ convW, float4* __restrict__ Wp) {
    int lane = threadIdx.x;  // 64
    int k = blockIdx.x;      // 64
    int l = blockIdx.y;      // 6
    const float* W1 = convW + ((size_t)l * 228 + k) * 128;
    const float* W2 = convW + ((size_t)l * 228 + 64 + k) * 128;
    Wp[((size_t)l * 64 + k) * 64 + lane] =
        make_float4(W1[lane], W1[lane + 64], W2[lane], W2[lane + 64]);
}

__global__ void k_embed(const int* __restrict__ an, const float* __restrict__ emb,
                        const float* __restrict__ W, const float* __restrict__ b,
                        float* __restrict__ x) {
    int c = threadIdx.x & 63, nl = threadIdx.x >> 6;
    int n = blockIdx.x * 4 + nl;
    if (n >= NN) return;
    const float* e = emb + (size_t)an[n] * 92;
    float acc = b[c];
#pragma unroll 4
    for (int k = 0; k < 92; k++) acc += e[k] * W[k * 64 + c];
    x[(size_t)n * 64 + c] = acc;
}

__global__ void k_hist(const int* __restrict__ dst, int* __restrict__ counts) {
    int e = blockIdx.x * 256 + threadIdx.x;
    if (e < EE) atomicAdd(&counts[dst[e]], 1);
}

__global__ void k_scan_local(const int* __restrict__ counts, int* __restrict__ rp,
                             int* __restrict__ bsum) {
    __shared__ int buf[1024];
    int b = blockIdx.x, tid = threadIdx.x;
    int i = b * 1024 + tid;
    int val = (i < NN) ? counts[i] : 0;
    buf[tid] = val;
    __syncthreads();
    for (int off = 1; off < 1024; off <<= 1) {
        int t = (tid >= off) ? buf[tid - off] : 0;
        __syncthreads();
        buf[tid] += t;
        __syncthreads();
    }
    if (i < NN) rp[i + 1] = buf[tid];
    if (tid == 1023) bsum[b] = buf[1023];
}

__global__ void k_scan_off(int* __restrict__ bsum, int nb) {
    if (threadIdx.x == 0) {
        int acc = 0;
        for (int b = 0; b < nb; b++) { int v = bsum[b]; bsum[b] = acc; acc += v; }
    }
}

__global__ void k_scan_add(int* __restrict__ rp, const int* __restrict__ bsum) {
    int b = blockIdx.x, tid = threadIdx.x;
    int i = b * 1024 + tid;
    if (i < NN) rp[i + 1] += bsum[b];
    if (b == 0 && tid == 0) rp[0] = 0;
}

// scatter + pack fused: ej[pos] = (src<<13) | j  (dst-sorted order)
__global__ void k_scatter(const int* __restrict__ src, const int* __restrict__ dst,
                          const float* __restrict__ dist, const int* __restrict__ rp,
                          int* __restrict__ cursor, unsigned* __restrict__ ej) {
    int e = blockIdx.x * 256 + threadIdx.x;
    if (e < EE) {
        int d = dst[e];
        int p = atomicAdd(&cursor[d], 1);
        float t = dist[e] * ((TS - 1.0f) / 6.0f);
        int j = (int)(t + 0.5f);
        if (j > TS - 1) j = TS - 1;
        ej[rp[d] + p] = ((unsigned)src[e] << 13) | (unsigned)j;
    }
}

// u,v: 4 nodes per wave, Wp float4 loads, readlane broadcast
__global__ void __launch_bounds__(256) k_uv(const float* __restrict__ x,
                                            const float4* __restrict__ Wp,
                                            __half2* __restrict__ up, __half2* __restrict__ vp) {
    int lane = threadIdx.x & 63;
    int wv = __builtin_amdgcn_readfirstlane(threadIdx.x >> 6);
    int n0 = (blockIdx.x * 4 + wv) * 4;
    float xa = x[(size_t)(n0 + 0) * 64 + lane];
    float xb = x[(size_t)(n0 + 1) * 64 + lane];
    float xc = x[(size_t)(n0 + 2) * 64 + lane];
    float xd = x[(size_t)(n0 + 3) * 64 + lane];
    float2 ua = {0, 0}, ub = {0, 0}, uc = {0, 0}, ud = {0, 0};
    float2 va = {0, 0}, vb = {0, 0}, vc = {0, 0}, vd = {0, 0};
#pragma unroll 8
    for (int k = 0; k < 64; k++) {
        float4 w = Wp[k * 64 + lane];
        float ka = __uint_as_float(__builtin_amdgcn_readlane(__float_as_uint(xa), k));
        float kb = __uint_as_float(__builtin_amdgcn_readlane(__float_as_uint(xb), k));
        float kc = __uint_as_float(__builtin_amdgcn_readlane(__float_as_uint(xc), k));
        float kd = __uint_as_float(__builtin_amdgcn_readlane(__float_as_uint(xd), k));
        ua.x += ka * w.x; ua.y += ka * w.y; va.x += ka * w.z; va.y += ka * w.w;
        ub.x += kb * w.x; ub.y += kb * w.y; vb.x += kb * w.z; vb.y += kb * w.w;
        uc.x += kc * w.x; uc.y += kc * w.y; vc.x += kc * w.z; vc.y += kc * w.w;
        ud.x += kd * w.x; ud.y += kd * w.y; vd.x += kd * w.z; vd.y += kd * w.w;
    }
    up[(size_t)(n0 + 0) * 64 + lane] = __floats2half2_rn(ua.x, ua.y);
    up[(size_t)(n0 + 1) * 64 + lane] = __floats2half2_rn(ub.x, ub.y);
    up[(size_t)(n0 + 2) * 64 + lane] = __floats2half2_rn(uc.x, uc.y);
    up[(size_t)(n0 + 3) * 64 + lane] = __floats2half2_rn(ud.x, ud.y);
    vp[(size_t)(n0 + 0) * 64 + lane] = __floats2half2_rn(va.x, va.y);
    vp[(size_t)(n0 + 1) * 64 + lane] = __floats2half2_rn(vb.x, vb.y);
    vp[(size_t)(n0 + 2) * 64 + lane] = __floats2half2_rn(vc.x, vc.y);
    vp[(size_t)(n0 + 3) * 64 + lane] = __floats2half2_rn(vd.x, vd.y);
}

// Two-edge-per-vmem gather group: lanes 0-31 carry edge 2p, lanes 32-63 edge 2p+1.
// Byte-identical reinterpret of half2[row][64] as float2[row][32]; each lane owns
// channel pairs (2k,2k+64) and (2k+1,2k+1+64).
#define EDGE_GROUP(P, BODY)                                                  \
    {                                                                        \
        unsigned el = ej[idx + lane];                                        \
        float2 vr[P], tr[P];                                                 \
        _Pragma("unroll")                                                    \
        for (int p = 0; p < P; p++) {                                        \
            unsigned eA = __builtin_amdgcn_readlane(el, 2 * p);              \
            unsigned eB = __builtin_amdgcn_readlane(el, 2 * p + 1);          \
            unsigned e = slot ? eB : eA;                                     \
            vr[p] = vq[(size_t)(e >> 13) * 32 + k];                          \
            tr[p] = tq[(size_t)(e & 8191u) * 32 + k];                        \
        }                                                                    \
        _Pragma("unroll")                                                    \
        for (int p = 0; p < P; p++) { BODY }                                 \
    }

#define STATS_BODY                                                           \
    float2 va = h2f(vr[p].x), vb = h2f(vr[p].y);                             \
    float2 ta = h2f(tr[p].x), tb = h2f(tr[p].y);                             \
    float z00 = u00 + va.x + ta.x, z10 = u10 + va.y + ta.y;                  \
    float z01 = u01 + vb.x + tb.x, z11 = u11 + vb.y + tb.y;                  \
    s00 += z00; q00 += z00 * z00; s10 += z10; q10 += z10 * z10;              \
    s01 += z01; q01 += z01 * z01; s11 += z11; q11 += z11 * z11;

#define AGG_BODY                                                             \
    float2 va = h2f(vr[p].x), vb = h2f(vr[p].y);                             \
    float2 ta = h2f(tr[p].x), tb = h2f(tr[p].y);                             \
    float z00 = (u00 + va.x + ta.x) * A1a + B1a;                             \
    float z10 = (u10 + va.y + ta.y) * A2a + B2a;                             \
    float z01 = (u01 + vb.x + tb.x) * A1b + B1b;                             \
    float z11 = (u11 + vb.y + tb.y) * A2b + B2b;                             \
    acc0 += sigmoid_fast(z00) * softplus_fast(z10);                          \
    acc1 += sigmoid_fast(z01) * softplus_fast(z11);

// pass A: BN stats only; 2 nodes per wave; paired-edge 512B gathers.
__global__ void __launch_bounds__(256) k_stats(
    const __half2* __restrict__ up, const __half2* __restrict__ vp,
    const __half2* __restrict__ Tn, const unsigned* __restrict__ ej,
    const int* __restrict__ rp, float* __restrict__ sums) {
    int lane = threadIdx.x & 63;
    int wv = __builtin_amdgcn_readfirstlane(threadIdx.x >> 6);
    int k = lane & 31;
    int slot = lane >> 5;
    const float2* vq = (const float2*)vp;
    const float2* tq = (const float2*)Tn;
    const float2* uq = (const float2*)up;
    float s00 = 0, s01 = 0, s10 = 0, s11 = 0;
    float q00 = 0, q01 = 0, q10 = 0, q11 = 0;
    for (int i = blockIdx.x * 4 + wv; i < NN; i += 10000) {
        float2 uw = uq[(size_t)i * 32 + k];
        float2 uA = h2f(uw.x), uB = h2f(uw.y);
        float u00 = uA.x, u10 = uA.y, u01 = uB.x, u11 = uB.y;
        int rs = __builtin_amdgcn_readfirstlane(rp[i]);
        int re = __builtin_amdgcn_readfirstlane(rp[i + 1]);
        int idx = rs;
        for (; idx + 16 <= re; idx += 16) EDGE_GROUP(8, STATS_BODY)
        if (idx + 8 <= re) { EDGE_GROUP(4, STATS_BODY) idx += 8; }
        if (idx + 4 <= re) { EDGE_GROUP(2, STATS_BODY) idx += 4; }
        if (idx + 2 <= re) { EDGE_GROUP(1, STATS_BODY) idx += 2; }
        if (idx < re && slot == 0) {
            unsigned e = ej[idx];
            float2 vr0 = vq[(size_t)(e >> 13) * 32 + k];
            float2 tr0 = tq[(size_t)(e & 8191u) * 32 + k];
            float2 va = h2f(vr0.x), vb = h2f(vr0.y);
            float2 ta = h2f(tr0.x), tb = h2f(tr0.y);
            float z00 = u00 + va.x + ta.x, z10 = u10 + va.y + ta.y;
            float z01 = u01 + vb.x + tb.x, z11 = u11 + vb.y + tb.y;
            s00 += z00; q00 += z00 * z00; s10 += z10; q10 += z10 * z10;
            s01 += z01; q01 += z01 * z01; s11 += z11; q11 += z11 * z11;
        }
    }
    // combine edge-slot halves (lanes l and l+32 hold same channels)
    s00 += __shfl_xor(s00, 32, 64); s01 += __shfl_xor(s01, 32, 64);
    s10 += __shfl_xor(s10, 32, 64); s11 += __shfl_xor(s11, 32, 64);
    q00 += __shfl_xor(q00, 32, 64); q01 += __shfl_xor(q01, 32, 64);
    q10 += __shfl_xor(q10, 32, 64); q11 += __shfl_xor(q11, 32, 64);
    __shared__ float red[4][32][9];
    if (slot == 0) {
        float* r = red[wv][k];
        r[0] = s00; r[1] = s01; r[2] = s10; r[3] = s11;
        r[4] = q00; r[5] = q01; r[6] = q10; r[7] = q11;
    }
    __syncthreads();
    if (wv == 0 && slot == 0) {
        for (int w = 1; w < 4; w++) {
            const float* r = red[w][k];
            s00 += r[0]; s01 += r[1]; s10 += r[2]; s11 += r[3];
            q00 += r[4]; q01 += r[5]; q10 += r[6]; q11 += r[7];
        }
        int c0 = 2 * k, c1 = 2 * k + 1;
        atomicAdd(&sums[c0], s00);        atomicAdd(&sums[c1], s01);
        atomicAdd(&sums[64 + c0], s10);   atomicAdd(&sums[64 + c1], s11);
        atomicAdd(&sums[128 + c0], q00);  atomicAdd(&sums[128 + c1], q01);
        atomicAdd(&sums[192 + c0], q10);  atomicAdd(&sums[192 + c1], q11);
    }
}

// pass B: re-gather + recompute z (paired-edge), inline BN fold,
// sigmoid*softplus, aggregate; LN + residual + softplus epilogue in shuffles.
__global__ void __launch_bounds__(256) k_agg(
    const __half2* __restrict__ up, const __half2* __restrict__ vp,
    const __half2* __restrict__ Tn, const unsigned* __restrict__ ej,
    const int* __restrict__ rp, const float* __restrict__ sums,
    const float* __restrict__ bng, const float* __restrict__ bnb,
    const float* __restrict__ lng, const float* __restrict__ lnb,
    int l, const float* __restrict__ xin, float* __restrict__ xout) {
    int lane = threadIdx.x & 63;
    int wv = __builtin_amdgcn_readfirstlane(threadIdx.x >> 6);
    int k = lane & 31;
    int slot = lane >> 5;
    int i = blockIdx.x * 4 + wv;
    int c0 = 2 * k, c1 = 2 * k + 1;
    const float2* vq = (const float2*)vp;
    const float2* tq = (const float2*)Tn;
    const float2* uq = (const float2*)up;

    const float2* s2 = (const float2*)sums;
    float2 sZ0 = s2[k];       // sum z0: c0,c1
    float2 sZ1 = s2[32 + k];  // sum z1
    float2 sQ0 = s2[64 + k];  // sum z0^2
    float2 sQ1 = s2[96 + k];  // sum z1^2
    const float2* bg = (const float2*)(bng + l * 128);
    const float2* bb = (const float2*)(bnb + l * 128);
    float2 g0 = bg[k], g1 = bg[32 + k];
    float2 b0 = bb[k], b1 = bb[32 + k];
    float mu;
    mu = sZ0.x * (1.0f / EE);
    float A1a = rsqrtf(sQ0.x * (1.0f / EE) - mu * mu + EPS) * g0.x;
    float B1a = b0.x - mu * A1a;
    mu = sZ0.y * (1.0f / EE);
    float A1b = rsqrtf(sQ0.y * (1.0f / EE) - mu * mu + EPS) * g0.y;
    float B1b = b0.y - mu * A1b;
    mu = sZ1.x * (1.0f / EE);
    float A2a = rsqrtf(sQ1.x * (1.0f / EE) - mu * mu + EPS) * g1.x;
    float B2a = b1.x - mu * A2a;
    mu = sZ1.y * (1.0f / EE);
    float A2b = rsqrtf(sQ1.y * (1.0f / EE) - mu * mu + EPS) * g1.y;
    float B2b = b1.y - mu * A2b;

    float2 uw = uq[(size_t)i * 32 + k];
    float2 uA = h2f(uw.x), uB = h2f(uw.y);
    float u00 = uA.x, u10 = uA.y, u01 = uB.x, u11 = uB.y;
    float2 xw = ((const float2*)xin)[(size_t)i * 32 + k];

    float acc0 = 0.f, acc1 = 0.f;
    int rs = __builtin_amdgcn_readfirstlane(rp[i]);
    int re = __builtin_amdgcn_readfirstlane(rp[i + 1]);
    int idx = rs;
    for (; idx + 16 <= re; idx += 16) EDGE_GROUP(8, AGG_BODY)
    if (idx + 8 <= re) { EDGE_GROUP(4, AGG_BODY) idx += 8; }
    if (idx + 4 <= re) { EDGE_GROUP(2, AGG_BODY) idx += 4; }
    if (idx + 2 <= re) { EDGE_GROUP(1, AGG_BODY) idx += 2; }
    if (idx < re && slot == 0) {
        unsigned e = ej[idx];
        float2 vr0 = vq[(size_t)(e >> 13) * 32 + k];
        float2 tr0 = tq[(size_t)(e & 8191u) * 32 + k];
        float2 va = h2f(vr0.x), vb = h2f(vr0.y);
        float2 ta = h2f(tr0.x), tb = h2f(tr0.y);
        float z00 = (u00 + va.x + ta.x) * A1a + B1a;
        float z10 = (u10 + va.y + ta.y) * A2a + B2a;
        float z01 = (u01 + vb.x + tb.x) * A1b + B1b;
        float z11 = (u11 + vb.y + tb.y) * A2b + B2b;
        acc0 += sigmoid_fast(z00) * softplus_fast(z10);
        acc1 += sigmoid_fast(z01) * softplus_fast(z11);
    }
    // combine edge-slot halves
    acc0 += __shfl_xor(acc0, 32, 64);
    acc1 += __shfl_xor(acc1, 32, 64);
    // LayerNorm across 64 channels (each half-wave holds all 64 via 2/lane)
    float s = acc0 + acc1;
#pragma unroll
    for (int off = 16; off; off >>= 1) s += __shfl_xor(s, off, 64);
    float mean = s * (1.0f / 64.0f);
    float e0 = acc0 - mean, e1 = acc1 - mean;
    float vv = e0 * e0 + e1 * e1;
#pragma unroll
    for (int off = 16; off; off >>= 1) vv += __shfl_xor(vv, off, 64);
    float r = rsqrtf(vv * (1.0f / 64.0f) + EPS);
    const float2* lg = (const float2*)(lng + l * 64);
    const float2* lb = (const float2*)(lnb + l * 64);
    float2 gg = lg[k], bbv = lb[k];
    float h0 = e0 * r * gg.x + bbv.x;
    float h1 = e1 * r * gg.y + bbv.y;
    float o0 = softplus_ref(h0 + xw.x);
    float o1 = softplus_ref(h1 + xw.y);
    if (slot == 0)
        ((float2*)xout)[(size_t)i * 32 + k] = make_float2(o0, o1);
}

// batch sorted -> graph row pointers by binary search
__global__ void k_gp(const int* __restrict__ batch, int* __restrict__ gp) {
    int g = threadIdx.x;
    if (g > GG) return;
    int lo = 0, hi = NN;
    while (lo < hi) {
        int mid = (lo + hi) >> 1;
        if (batch[mid] < g) lo = mid + 1; else hi = mid;
    }
    gp[g] = lo;
}

// atomic-free segmented mean-pool
__global__ void k_pool2(const float* __restrict__ x, const int* __restrict__ gp,
                        float* __restrict__ mols) {
    int g = blockIdx.x;
    int lane = threadIdx.x & 63, slot = threadIdx.x >> 6;
    int s0 = gp[g], s1 = gp[g + 1];
    float acc = 0.f;
    for (int n = s0 + slot; n < s1; n += 4) acc += x[(size_t)n * 64 + lane];
    __shared__ float red[4][64];
    red[slot][lane] = acc;
    __syncthreads();
    if (slot == 0) {
        float a = red[0][lane] + red[1][lane] + red[2][lane] + red[3][lane];
        float cc = fmaxf((float)(s1 - s0), 1.0f);
        mols[g * 64 + lane] = a / cc;
    }
}

__global__ void k_mlp(const float* __restrict__ mols,
                      const float* __restrict__ fc1W, const float* __restrict__ fc1b,
                      const float* __restrict__ fcsW, const float* __restrict__ fcsb,
                      const float* __restrict__ outW, const float* __restrict__ outb,
                      float* __restrict__ y) {
    int g = blockIdx.x, t = threadIdx.x; // 128 threads
    __shared__ float m[64];
    __shared__ float h[128];
    __shared__ float rbuf[128];
    if (t < 64) m[t] = mols[g * 64 + t];
    __syncthreads();
    float a = fc1b[t];
#pragma unroll 4
    for (int k = 0; k < 64; k++) a += m[k] * fc1W[k * 128 + t];
    h[t] = softplus_ref(a);
    __syncthreads();
    for (int i = 0; i < 3; i++) {
        float b = fcsb[i * 128 + t];
#pragma unroll 4
        for (int k = 0; k < 128; k++) b += h[k] * fcsW[((size_t)i * 128 + k) * 128 + t];
        __syncthreads();
        h[t] = softplus_ref(b);
        __syncthreads();
    }
    rbuf[t] = h[t] * outW[t];
    __syncthreads();
    if (t < 64) {
        float s2 = rbuf[t] + rbuf[t + 64];
#pragma unroll
        for (int off = 32; off; off >>= 1) s2 += __shfl_xor(s2, off, 64);
        if (t == 0) y[g] = s2 + outb[0];
    }
}

extern "C" void kernel_launch(void* const* d_in, const int* in_sizes, int n_in,
                              void* d_out, int out_size, void* d_ws, size_t ws_size,
                              hipStream_t stream) {
    const int*   an    = (const int*)d_in[0];
    const int*   nbr   = (const int*)d_in[1];
    const float* dist  = (const float*)d_in[2];
    const int*   batch = (const int*)d_in[3];
    const float* emb   = (const float*)d_in[4];
    const float* nucW  = (const float*)d_in[5];
    const float* nucB  = (const float*)d_in[6];
    const float* convW = (const float*)d_in[7];
    const float* convB = (const float*)d_in[8];
    const float* bng   = (const float*)d_in[9];
    const float* bnb   = (const float*)d_in[10];
    const float* lng   = (const float*)d_in[11];
    const float* lnb   = (const float*)d_in[12];
    const float* fc1W  = (const float*)d_in[13];
    const float* fc1b  = (const float*)d_in[14];
    const float* fcsW  = (const float*)d_in[15];
    const float* fcsb  = (const float*)d_in[16];
    const float* outW  = (const float*)d_in[17];
    const float* outb  = (const float*)d_in[18];
    const int* srcI = nbr;
    const int* dstI = nbr + EE;

    char* base = (char*)d_ws;
    size_t off = 0;
    auto alloc = [&](size_t b) { size_t r = off; off += (b + 255) & ~(size_t)255; return r; };
    float*    gtab   = (float*)(base + alloc((size_t)TS * 100 * 4));
    __half2*  Tall   = (__half2*)(base + alloc((size_t)6 * TS * 64 * 4));
    float4*   Wp     = (float4*)(base + alloc((size_t)6 * 64 * 64 * 16));
    float*    x0     = (float*)(base + alloc((size_t)NN * 64 * 4));
    float*    x1     = (float*)(base + alloc((size_t)NN * 64 * 4));
    __half2*  up     = (__half2*)(base + alloc((size_t)NN * 64 * 4));
    __half2*  vp     = (__half2*)(base + alloc((size_t)NN * 64 * 4));
    float*    sums6  = (float*)(base + alloc((size_t)6 * 256 * 4));
    int*      counts = (int*)(base + alloc((size_t)NN * 4));
    int*      cursor = (int*)(base + alloc((size_t)NN * 4));
    int*      rp     = (int*)(base + alloc((size_t)(NN + 1) * 4));
    int*      bsum   = (int*)(base + alloc(64 * 4));
    unsigned* ej     = (unsigned*)(base + alloc((size_t)(EE + 64) * 4));
    float*    mols   = (float*)(base + alloc((size_t)GG * 64 * 4));
    int*      gp     = (int*)(base + alloc((size_t)(GG + 1) * 4));

    hipMemsetAsync(counts, 0, (size_t)NN * 4, stream);
    hipMemsetAsync(cursor, 0, (size_t)NN * 4, stream);
    hipMemsetAsync(sums6, 0, (size_t)6 * 256 * 4, stream);

    k_gtab<<<(TS * 100 + 255) / 256, 256, 0, stream>>>(gtab);
    k_build_T<<<dim3(TS / 16, 6), 256, 0, stream>>>(gtab, convW, convB, Tall);
    k_prepW<<<dim3(64, 6), 64, 0, stream>>>(convW, Wp);
    k_embed<<<(NN + 3) / 4, 256, 0, stream>>>(an, emb, nucW, nucB, x0);
    k_hist<<<(EE + 255) / 256, 256, 0, stream>>>(dstI, counts);
    const int NB = (NN + 1023) / 1024;
    k_scan_local<<<NB, 1024, 0, stream>>>(counts, rp, bsum);
    k_scan_off<<<1, 64, 0, stream>>>(bsum, NB);
    k_scan_add<<<NB, 1024, 0, stream>>>(rp, bsum);
    k_scatter<<<(EE + 255) / 256, 256, 0, stream>>>(srcI, dstI, dist, rp, cursor, ej);
    k_gp<<<1, 128, 0, stream>>>(batch, gp);

    float* xin = x0;
    float* xout = x1;
    for (int l = 0; l < 6; l++) {
        k_uv<<<NN / 16, 256, 0, stream>>>(xin, Wp + (size_t)l * 64 * 64, up, vp);
        const __half2* Tnl = Tall + (size_t)l * TS * 64;
        float* sums = sums6 + (size_t)l * 256;
        k_stats<<<2500, 256, 0, stream>>>(up, vp, Tnl, ej, rp, sums);
        k_agg<<<NN / 4, 256, 0, stream>>>(up, vp, Tnl, ej, rp, sums,
                                          bng, bnb, lng, lnb, l, xin, xout);
        float* tmp = xin; xin = xout; xout = tmp;
    }
    k_pool2<<<GG, 256, 0, stream>>>(xin, gp, mols);
    k_mlp<<<GG, 128, 0, stream>>>(mols, fc1W, fc1b, fcsW, fcsb, outW, outb, (float*)d_out);
}

// Round 3
// 1022.539 us; speedup vs baseline: 1.4514x; 1.4514x over previous
//
#include <hip/hip_runtime.h>
#include <hip/hip_fp16.h>
#include <cmath>

#define NN 20000
#define EE 500000
#define GG 64
#define TS 8192
#define SW 8192   // k_stats wave count (edge-balanced)
#define EPS 1e-5f

__device__ __forceinline__ float softplus_ref(float x) {
    return fmaxf(x, 0.f) + log1pf(__expf(-fabsf(x)));
}
__device__ __forceinline__ float softplus_fast(float x) {
    return fmaxf(x, 0.f) + __logf(1.0f + __expf(-fabsf(x)));
}
__device__ __forceinline__ float sigmoid_fast(float x) {
    return __builtin_amdgcn_rcpf(1.0f + __expf(-x));
}

// gaussian table: g[s][k] = exp(coeff*(d_s - o_k)^2)
__global__ void k_gtab(float* __restrict__ g) {
    int i = blockIdx.x * 256 + threadIdx.x;
    if (i >= TS * 100) return;
    int s = i / 100, k = i - 100 * s;
    float d = s * (6.0f / (TS - 1.0f));
    float o = k * (6.0f / 99.0f);
    float step = 6.0f / 99.0f;
    float coeff = -0.5f / (step * step);
    float df = d - o;
    g[i] = __expf(coeff * df * df);
}

// Nearest-neighbor table, paired channels: Tn[l][s][t] = half2(T[c=t], T[c=t+64])
__global__ void __launch_bounds__(256) k_build_T(
    const float* __restrict__ g, const float* __restrict__ convW,
    const float* __restrict__ convB, __half2* __restrict__ Tn) {
    int lane = threadIdx.x & 63;
    int wv = __builtin_amdgcn_readfirstlane(threadIdx.x >> 6);
    int l = blockIdx.y;
    int s0 = blockIdx.x * 16 + wv * 4;
    const float* w = convW + ((size_t)l * 228 + 128) * 128;
    const float* g0 = g + (size_t)s0 * 100;
    float b0 = convB[l * 128 + lane], b1 = convB[l * 128 + lane + 64];
    float2 a0 = {b0, b1}, a1 = {b0, b1}, a2 = {b0, b1}, a3 = {b0, b1};
#pragma unroll 4
    for (int k = 0; k < 100; k++) {
        float w0 = w[k * 128 + lane];
        float w1 = w[k * 128 + lane + 64];
        float ga = g0[k], gb = g0[100 + k], gc = g0[200 + k], gd = g0[300 + k];
        a0.x += ga * w0; a0.y += ga * w1;
        a1.x += gb * w0; a1.y += gb * w1;
        a2.x += gc * w0; a2.y += gc * w1;
        a3.x += gd * w0; a3.y += gd * w1;
    }
    Tn[((size_t)l * TS + s0 + 0) * 64 + lane] = __floats2half2_rn(a0.x, a0.y);
    Tn[((size_t)l * TS + s0 + 1) * 64 + lane] = __floats2half2_rn(a1.x, a1.y);
    Tn[((size_t)l * TS + s0 + 2) * 64 + lane] = __floats2half2_rn(a2.x, a2.y);
    Tn[((size_t)l * TS + s0 + 3) * 64 + lane] = __floats2half2_rn(a3.x, a3.y);
}

// Wp[l][k][lane] = (W1[k,lane], W1[k,lane+64], W2[k,lane], W2[k,lane+64])
__global__ void k_prepW(const float* __restrict__ convW, float4* __restrict__ Wp) {
    int lane = threadIdx.x;  // 64
    int k = blockIdx.x;      // 64
    int l = blockIdx.y;      // 6
    const float* W1 = convW + ((size_t)l * 228 + k) * 128;
    const float* W2 = convW + ((size_t)l * 228 + 64 + k) * 128;
    Wp[((size_t)l * 64 + k) * 64 + lane] =
        make_float4(W1[lane], W1[lane + 64], W2[lane], W2[lane + 64]);
}

__global__ void k_embed(const int* __restrict__ an, const float* __restrict__ emb,
                        const float* __restrict__ W, const float* __restrict__ b,
                        float* __restrict__ x) {
    int c = threadIdx.x & 63, nl = threadIdx.x >> 6;
    int n = blockIdx.x * 4 + nl;
    if (n >= NN) return;
    const float* e = emb + (size_t)an[n] * 92;
    float acc = b[c];
#pragma unroll 4
    for (int k = 0; k < 92; k++) acc += e[k] * W[k * 64 + c];
    x[(size_t)n * 64 + c] = acc;
}

__global__ void k_hist(const int* __restrict__ dst, int* __restrict__ counts) {
    int e = blockIdx.x * 256 + threadIdx.x;
    if (e < EE) atomicAdd(&counts[dst[e]], 1);
}

__global__ void k_scan_local(const int* __restrict__ counts, int* __restrict__ rp,
                             int* __restrict__ bsum) {
    __shared__ int buf[1024];
    int b = blockIdx.x, tid = threadIdx.x;
    int i = b * 1024 + tid;
    int val = (i < NN) ? counts[i] : 0;
    buf[tid] = val;
    __syncthreads();
    for (int off = 1; off < 1024; off <<= 1) {
        int t = (tid >= off) ? buf[tid - off] : 0;
        __syncthreads();
        buf[tid] += t;
        __syncthreads();
    }
    if (i < NN) rp[i + 1] = buf[tid];
    if (tid == 1023) bsum[b] = buf[1023];
}

__global__ void k_scan_off(int* __restrict__ bsum, int nb) {
    if (threadIdx.x == 0) {
        int acc = 0;
        for (int b = 0; b < nb; b++) { int v = bsum[b]; bsum[b] = acc; acc += v; }
    }
}

__global__ void k_scan_add(int* __restrict__ rp, const int* __restrict__ bsum) {
    int b = blockIdx.x, tid = threadIdx.x;
    int i = b * 1024 + tid;
    if (i < NN) rp[i + 1] += bsum[b];
    if (b == 0 && tid == 0) rp[0] = 0;
}

// wave -> start node for edge-balanced k_stats (removes per-wave binary search)
__global__ void k_wsn(const int* __restrict__ rp, int* __restrict__ wsn) {
    int w = blockIdx.x * 256 + threadIdx.x;
    if (w >= SW) return;
    int e0 = (int)((long long)w * EE / SW);
    int lo = 0, hi = NN;
    while (lo + 1 < hi) {
        int mid = (lo + hi) >> 1;
        if (rp[mid] <= e0) lo = mid; else hi = mid;
    }
    wsn[w] = lo;
}

// scatter + pack fused: ej[pos] = (src<<13) | j  (dst-sorted order)
__global__ void k_scatter(const int* __restrict__ src, const int* __restrict__ dst,
                          const float* __restrict__ dist, const int* __restrict__ rp,
                          int* __restrict__ cursor, unsigned* __restrict__ ej) {
    int e = blockIdx.x * 256 + threadIdx.x;
    if (e < EE) {
        int d = dst[e];
        int p = atomicAdd(&cursor[d], 1);
        float t = dist[e] * ((TS - 1.0f) / 6.0f);
        int j = (int)(t + 0.5f);
        if (j > TS - 1) j = TS - 1;
        ej[rp[d] + p] = ((unsigned)src[e] << 13) | (unsigned)j;
    }
}

// u,v: 4 nodes per wave, Wp float4 loads, readlane broadcast
__global__ void __launch_bounds__(256) k_uv(const float* __restrict__ x,
                                            const float4* __restrict__ Wp,
                                            __half2* __restrict__ up, __half2* __restrict__ vp) {
    int lane = threadIdx.x & 63;
    int wv = __builtin_amdgcn_readfirstlane(threadIdx.x >> 6);
    int n0 = (blockIdx.x * 4 + wv) * 4;
    float xa = x[(size_t)(n0 + 0) * 64 + lane];
    float xb = x[(size_t)(n0 + 1) * 64 + lane];
    float xc = x[(size_t)(n0 + 2) * 64 + lane];
    float xd = x[(size_t)(n0 + 3) * 64 + lane];
    float2 ua = {0, 0}, ub = {0, 0}, uc = {0, 0}, ud = {0, 0};
    float2 va = {0, 0}, vb = {0, 0}, vc = {0, 0}, vd = {0, 0};
#pragma unroll 8
    for (int k = 0; k < 64; k++) {
        float4 w = Wp[k * 64 + lane];
        float ka = __uint_as_float(__builtin_amdgcn_readlane(__float_as_uint(xa), k));
        float kb = __uint_as_float(__builtin_amdgcn_readlane(__float_as_uint(xb), k));
        float kc = __uint_as_float(__builtin_amdgcn_readlane(__float_as_uint(xc), k));
        float kd = __uint_as_float(__builtin_amdgcn_readlane(__float_as_uint(xd), k));
        ua.x += ka * w.x; ua.y += ka * w.y; va.x += ka * w.z; va.y += ka * w.w;
        ub.x += kb * w.x; ub.y += kb * w.y; vb.x += kb * w.z; vb.y += kb * w.w;
        uc.x += kc * w.x; uc.y += kc * w.y; vc.x += kc * w.z; vc.y += kc * w.w;
        ud.x += kd * w.x; ud.y += kd * w.y; vd.x += kd * w.z; vd.y += kd * w.w;
    }
    up[(size_t)(n0 + 0) * 64 + lane] = __floats2half2_rn(ua.x, ua.y);
    up[(size_t)(n0 + 1) * 64 + lane] = __floats2half2_rn(ub.x, ub.y);
    up[(size_t)(n0 + 2) * 64 + lane] = __floats2half2_rn(uc.x, uc.y);
    up[(size_t)(n0 + 3) * 64 + lane] = __floats2half2_rn(ud.x, ud.y);
    vp[(size_t)(n0 + 0) * 64 + lane] = __floats2half2_rn(va.x, va.y);
    vp[(size_t)(n0 + 1) * 64 + lane] = __floats2half2_rn(vb.x, vb.y);
    vp[(size_t)(n0 + 2) * 64 + lane] = __floats2half2_rn(vc.x, vc.y);
    vp[(size_t)(n0 + 3) * 64 + lane] = __floats2half2_rn(vd.x, vd.y);
}

#define SGRP(P)                                                              \
    {                                                                        \
        unsigned e[P];                                                       \
        _Pragma("unroll")                                                    \
        for (int t = 0; t < P; t++) e[t] = ej[idx + t];                      \
        __half2 vh[P], th[P];                                                \
        _Pragma("unroll")                                                    \
        for (int t = 0; t < P; t++) {                                        \
            vh[t] = vp[(size_t)(e[t] >> 13) * 64 + lane];                    \
            th[t] = Tn[(size_t)(e[t] & 8191u) * 64 + lane];                  \
        }                                                                    \
        _Pragma("unroll")                                                    \
        for (int t = 0; t < P; t++) {                                        \
            float2 vv = __half22float2(vh[t]);                               \
            float2 tt = __half22float2(th[t]);                               \
            float z0 = uu.x + vv.x + tt.x;                                   \
            float z1 = uu.y + vv.y + tt.y;                                   \
            sx += z0; qx += z0 * z0;                                         \
            sy += z1; qy += z1 * z1;                                         \
        }                                                                    \
    }

// pass A: BN stats only; edge-balanced waves (61 edges/wave), 8-deep gather groups.
__global__ void __launch_bounds__(256) k_stats(
    const __half2* __restrict__ up, const __half2* __restrict__ vp,
    const __half2* __restrict__ Tn, const unsigned* __restrict__ ej,
    const int* __restrict__ rp, const int* __restrict__ wsn,
    float* __restrict__ sums) {
    int lane = threadIdx.x & 63;
    int wv = __builtin_amdgcn_readfirstlane(threadIdx.x >> 6);
    int w = blockIdx.x * 4 + wv;
    int e0 = (int)((long long)w * EE / SW);
    int e1 = (int)((long long)(w + 1) * EE / SW);
    int n = __builtin_amdgcn_readfirstlane(wsn[w]);
    int rend = __builtin_amdgcn_readfirstlane(rp[n + 1]);
    float sx = 0.f, sy = 0.f, qx = 0.f, qy = 0.f;
    int idx = e0;
    while (idx < e1) {
        while (idx >= rend) {
            ++n;
            rend = __builtin_amdgcn_readfirstlane(rp[n + 1]);
        }
        float2 uu = __half22float2(up[(size_t)n * 64 + lane]);
        int stop = (e1 < rend) ? e1 : rend;
        for (; idx + 8 <= stop; idx += 8) SGRP(8)
        if (idx + 4 <= stop) { SGRP(4) idx += 4; }
        if (idx + 2 <= stop) { SGRP(2) idx += 2; }
        if (idx < stop) { SGRP(1) idx += 1; }
    }
    __shared__ float red[4][64][4];
    red[wv][lane][0] = sx; red[wv][lane][1] = sy;
    red[wv][lane][2] = qx; red[wv][lane][3] = qy;
    __syncthreads();
    if (wv == 0) {
        for (int r = 1; r < 4; r++) {
            sx += red[r][lane][0]; sy += red[r][lane][1];
            qx += red[r][lane][2]; qy += red[r][lane][3];
        }
        atomicAdd(&sums[lane], sx);
        atomicAdd(&sums[lane + 64], sy);
        atomicAdd(&sums[128 + lane], qx);
        atomicAdd(&sums[192 + lane], qy);
    }
}

// pass B: re-gather + recompute z, inline BN fold, sigmoid*softplus, aggregate;
// LN + residual + softplus epilogue in shuffles.
__global__ void __launch_bounds__(256) k_agg(
    const __half2* __restrict__ up, const __half2* __restrict__ vp,
    const __half2* __restrict__ Tn, const unsigned* __restrict__ ej,
    const int* __restrict__ rp, const float* __restrict__ sums,
    const float* __restrict__ bng, const float* __restrict__ bnb,
    const float* __restrict__ lng, const float* __restrict__ lnb,
    int l, const float* __restrict__ xin, float* __restrict__ xout) {
    int lane = threadIdx.x & 63;
    int wv = __builtin_amdgcn_readfirstlane(threadIdx.x >> 6);
    int i = blockIdx.x * 4 + wv;
    float mu1 = sums[lane] * (1.0f / EE);
    float var1 = sums[128 + lane] * (1.0f / EE) - mu1 * mu1;
    float A1 = rsqrtf(var1 + EPS) * bng[l * 128 + lane];
    float B1 = bnb[l * 128 + lane] - mu1 * A1;
    float mu2 = sums[64 + lane] * (1.0f / EE);
    float var2 = sums[192 + lane] * (1.0f / EE) - mu2 * mu2;
    float A2 = rsqrtf(var2 + EPS) * bng[l * 128 + 64 + lane];
    float B2 = bnb[l * 128 + 64 + lane] - mu2 * A2;

    float2 uu = __half22float2(up[(size_t)i * 64 + lane]);
    float xr = xin[(size_t)i * 64 + lane];
    float acc = 0.f;
    int rs = __builtin_amdgcn_readfirstlane(rp[i]);
    int re = __builtin_amdgcn_readfirstlane(rp[i + 1]);
    int idx = rs;
    for (; idx + 8 <= re; idx += 8) {
        unsigned e[8];
#pragma unroll
        for (int t = 0; t < 8; t++) e[t] = ej[idx + t];
        __half2 vh[8], th[8];
#pragma unroll
        for (int t = 0; t < 8; t++) {
            vh[t] = vp[(size_t)(e[t] >> 13) * 64 + lane];
            th[t] = Tn[(size_t)(e[t] & 8191u) * 64 + lane];
        }
#pragma unroll
        for (int t = 0; t < 8; t++) {
            float2 vv = __half22float2(vh[t]);
            float2 tt = __half22float2(th[t]);
            float z0 = (uu.x + vv.x + tt.x) * A1 + B1;
            float z1 = (uu.y + vv.y + tt.y) * A2 + B2;
            acc += sigmoid_fast(z0) * softplus_fast(z1);
        }
    }
    for (; idx < re; ++idx) {
        unsigned e = ej[idx];
        float2 vv = __half22float2(vp[(size_t)(e >> 13) * 64 + lane]);
        float2 tt = __half22float2(Tn[(size_t)(e & 8191u) * 64 + lane]);
        float z0 = (uu.x + vv.x + tt.x) * A1 + B1;
        float z1 = (uu.y + vv.y + tt.y) * A2 + B2;
        acc += sigmoid_fast(z0) * softplus_fast(z1);
    }
    float s = acc;
#pragma unroll
    for (int off = 32; off; off >>= 1) s += __shfl_xor(s, off, 64);
    float mean = s * (1.0f / 64.0f);
    float e0v = acc - mean;
    float vv2 = e0v * e0v;
#pragma unroll
    for (int off = 32; off; off >>= 1) vv2 += __shfl_xor(vv2, off, 64);
    float var = vv2 * (1.0f / 64.0f);
    float h = e0v * rsqrtf(var + EPS) * lng[l * 64 + lane] + lnb[l * 64 + lane];
    xout[(size_t)i * 64 + lane] = softplus_ref(h + xr);
}

// batch sorted -> graph row pointers by binary search
__global__ void k_gp(const int* __restrict__ batch, int* __restrict__ gp) {
    int g = threadIdx.x;
    if (g > GG) return;
    int lo = 0, hi = NN;
    while (lo < hi) {
        int mid = (lo + hi) >> 1;
        if (batch[mid] < g) lo = mid + 1; else hi = mid;
    }
    gp[g] = lo;
}

// atomic-free segmented mean-pool
__global__ void k_pool2(const float* __restrict__ x, const int* __restrict__ gp,
                        float* __restrict__ mols) {
    int g = blockIdx.x;
    int lane = threadIdx.x & 63, slot = threadIdx.x >> 6;
    int s0 = gp[g], s1 = gp[g + 1];
    float acc = 0.f;
    for (int n = s0 + slot; n < s1; n += 4) acc += x[(size_t)n * 64 + lane];
    __shared__ float red[4][64];
    red[slot][lane] = acc;
    __syncthreads();
    if (slot == 0) {
        float a = red[0][lane] + red[1][lane] + red[2][lane] + red[3][lane];
        float cc = fmaxf((float)(s1 - s0), 1.0f);
        mols[g * 64 + lane] = a / cc;
    }
}

__global__ void k_mlp(const float* __restrict__ mols,
                      const float* __restrict__ fc1W, const float* __restrict__ fc1b,
                      const float* __restrict__ fcsW, const float* __restrict__ fcsb,
                      const float* __restrict__ outW, const float* __restrict__ outb,
                      float* __restrict__ y) {
    int g = blockIdx.x, t = threadIdx.x; // 128 threads
    __shared__ float m[64];
    __shared__ float h[128];
    __shared__ float rbuf[128];
    if (t < 64) m[t] = mols[g * 64 + t];
    __syncthreads();
    float a = fc1b[t];
#pragma unroll 4
    for (int k = 0; k < 64; k++) a += m[k] * fc1W[k * 128 + t];
    h[t] = softplus_ref(a);
    __syncthreads();
    for (int i = 0; i < 3; i++) {
        float b = fcsb[i * 128 + t];
#pragma unroll 4
        for (int k = 0; k < 128; k++) b += h[k] * fcsW[((size_t)i * 128 + k) * 128 + t];
        __syncthreads();
        h[t] = softplus_ref(b);
        __syncthreads();
    }
    rbuf[t] = h[t] * outW[t];
    __syncthreads();
    if (t < 64) {
        float s2 = rbuf[t] + rbuf[t + 64];
#pragma unroll
        for (int off = 32; off; off >>= 1) s2 += __shfl_xor(s2, off, 64);
        if (t == 0) y[g] = s2 + outb[0];
    }
}

extern "C" void kernel_launch(void* const* d_in, const int* in_sizes, int n_in,
                              void* d_out, int out_size, void* d_ws, size_t ws_size,
                              hipStream_t stream) {
    const int*   an    = (const int*)d_in[0];
    const int*   nbr   = (const int*)d_in[1];
    const float* dist  = (const float*)d_in[2];
    const int*   batch = (const int*)d_in[3];
    const float* emb   = (const float*)d_in[4];
    const float* nucW  = (const float*)d_in[5];
    const float* nucB  = (const float*)d_in[6];
    const float* convW = (const float*)d_in[7];
    const float* convB = (const float*)d_in[8];
    const float* bng   = (const float*)d_in[9];
    const float* bnb   = (const float*)d_in[10];
    const float* lng   = (const float*)d_in[11];
    const float* lnb   = (const float*)d_in[12];
    const float* fc1W  = (const float*)d_in[13];
    const float* fc1b  = (const float*)d_in[14];
    const float* fcsW  = (const float*)d_in[15];
    const float* fcsb  = (const float*)d_in[16];
    const float* outW  = (const float*)d_in[17];
    const float* outb  = (const float*)d_in[18];
    const int* srcI = nbr;
    const int* dstI = nbr + EE;

    char* base = (char*)d_ws;
    size_t off = 0;
    auto alloc = [&](size_t b) { size_t r = off; off += (b + 255) & ~(size_t)255; return r; };
    float*    gtab   = (float*)(base + alloc((size_t)TS * 100 * 4));
    __half2*  Tall   = (__half2*)(base + alloc((size_t)6 * TS * 64 * 4));
    float4*   Wp     = (float4*)(base + alloc((size_t)6 * 64 * 64 * 16));
    float*    x0     = (float*)(base + alloc((size_t)NN * 64 * 4));
    float*    x1     = (float*)(base + alloc((size_t)NN * 64 * 4));
    __half2*  up     = (__half2*)(base + alloc((size_t)NN * 64 * 4));
    __half2*  vp     = (__half2*)(base + alloc((size_t)NN * 64 * 4));
    float*    sums6  = (float*)(base + alloc((size_t)6 * 256 * 4));
    int*      counts = (int*)(base + alloc((size_t)NN * 4));
    int*      cursor = (int*)(base + alloc((size_t)NN * 4));
    int*      rp     = (int*)(base + alloc((size_t)(NN + 1) * 4));
    int*      bsum   = (int*)(base + alloc(64 * 4));
    unsigned* ej     = (unsigned*)(base + alloc((size_t)(EE + 64) * 4));
    int*      wsn    = (int*)(base + alloc((size_t)SW * 4));
    float*    mols   = (float*)(base + alloc((size_t)GG * 64 * 4));
    int*      gp     = (int*)(base + alloc((size_t)(GG + 1) * 4));

    hipMemsetAsync(counts, 0, (size_t)NN * 4, stream);
    hipMemsetAsync(cursor, 0, (size_t)NN * 4, stream);
    hipMemsetAsync(sums6, 0, (size_t)6 * 256 * 4, stream);

    k_gtab<<<(TS * 100 + 255) / 256, 256, 0, stream>>>(gtab);
    k_build_T<<<dim3(TS / 16, 6), 256, 0, stream>>>(gtab, convW, convB, Tall);
    k_prepW<<<dim3(64, 6), 64, 0, stream>>>(convW, Wp);
    k_embed<<<(NN + 3) / 4, 256, 0, stream>>>(an, emb, nucW, nucB, x0);
    k_hist<<<(EE + 255) / 256, 256, 0, stream>>>(dstI, counts);
    const int NB = (NN + 1023) / 1024;
    k_scan_local<<<NB, 1024, 0, stream>>>(counts, rp, bsum);
    k_scan_off<<<1, 64, 0, stream>>>(bsum, NB);
    k_scan_add<<<NB, 1024, 0, stream>>>(rp, bsum);
    k_wsn<<<SW / 256, 256, 0, stream>>>(rp, wsn);
    k_scatter<<<(EE + 255) / 256, 256, 0, stream>>>(srcI, dstI, dist, rp, cursor, ej);
    k_gp<<<1, 128, 0, stream>>>(batch, gp);

    float* xin = x0;
    float* xout = x1;
    for (int l = 0; l < 6; l++) {
        k_uv<<<NN / 16, 256, 0, stream>>>(xin, Wp + (size_t)l * 64 * 64, up, vp);
        const __half2* Tnl = Tall + (size_t)l * TS * 64;
        float* sums = sums6 + (size_t)l * 256;
        k_stats<<<SW / 4, 256, 0, stream>>>(up, vp, Tnl, ej, rp, wsn, sums);
        k_agg<<<NN / 4, 256, 0, stream>>>(up, vp, Tnl, ej, rp, sums,
                                          bng, bnb, lng, lnb, l, xin, xout);
        float* tmp = xin; xin = xout; xout = tmp;
    }
    k_pool2<<<GG, 256, 0, stream>>>(xin, gp, mols);
    k_mlp<<<GG, 128, 0, stream>>>(mols, fc1W, fc1b, fcsW, fcsb, outW, outb, (float*)d_out);
}

// Round 4
// 955.695 us; speedup vs baseline: 1.5530x; 1.0699x over previous
//
#include <hip/hip_runtime.h>
#include <hip/hip_fp16.h>
#include <cmath>

#define NN 20000
#define EE 500000
#define GG 64
#define TS 8192
#define SW 4096   // k_stats waves per channel-half (edge-balanced)
#define EPS 1e-5f

__device__ __forceinline__ float softplus_ref(float x) {
    return fmaxf(x, 0.f) + log1pf(__expf(-fabsf(x)));
}
__device__ __forceinline__ float softplus_fast(float x) {
    return fmaxf(x, 0.f) + __logf(1.0f + __expf(-fabsf(x)));
}
__device__ __forceinline__ float sigmoid_fast(float x) {
    return __builtin_amdgcn_rcpf(1.0f + __expf(-x));
}

// gaussian table: g[s][k] = exp(coeff*(d_s - o_k)^2)
__global__ void k_gtab(float* __restrict__ g) {
    int i = blockIdx.x * 256 + threadIdx.x;
    if (i >= TS * 100) return;
    int s = i / 100, k = i - 100 * s;
    float d = s * (6.0f / (TS - 1.0f));
    float o = k * (6.0f / 99.0f);
    float step = 6.0f / 99.0f;
    float coeff = -0.5f / (step * step);
    float df = d - o;
    g[i] = __expf(coeff * df * df);
}

// Nearest-neighbor table, paired channels: Tn[l][s][t] = half2(T[c=t], T[c=t+64])
__global__ void __launch_bounds__(256) k_build_T(
    const float* __restrict__ g, const float* __restrict__ convW,
    const float* __restrict__ convB, __half2* __restrict__ Tn) {
    int lane = threadIdx.x & 63;
    int wv = __builtin_amdgcn_readfirstlane(threadIdx.x >> 6);
    int l = blockIdx.y;
    int s0 = blockIdx.x * 16 + wv * 4;
    const float* w = convW + ((size_t)l * 228 + 128) * 128;
    const float* g0 = g + (size_t)s0 * 100;
    float b0 = convB[l * 128 + lane], b1 = convB[l * 128 + lane + 64];
    float2 a0 = {b0, b1}, a1 = {b0, b1}, a2 = {b0, b1}, a3 = {b0, b1};
#pragma unroll 4
    for (int k = 0; k < 100; k++) {
        float w0 = w[k * 128 + lane];
        float w1 = w[k * 128 + lane + 64];
        float ga = g0[k], gb = g0[100 + k], gc = g0[200 + k], gd = g0[300 + k];
        a0.x += ga * w0; a0.y += ga * w1;
        a1.x += gb * w0; a1.y += gb * w1;
        a2.x += gc * w0; a2.y += gc * w1;
        a3.x += gd * w0; a3.y += gd * w1;
    }
    Tn[((size_t)l * TS + s0 + 0) * 64 + lane] = __floats2half2_rn(a0.x, a0.y);
    Tn[((size_t)l * TS + s0 + 1) * 64 + lane] = __floats2half2_rn(a1.x, a1.y);
    Tn[((size_t)l * TS + s0 + 2) * 64 + lane] = __floats2half2_rn(a2.x, a2.y);
    Tn[((size_t)l * TS + s0 + 3) * 64 + lane] = __floats2half2_rn(a3.x, a3.y);
}

// Wp[l][k][lane] = (W1[k,lane], W1[k,lane+64], W2[k,lane], W2[k,lane+64])
__global__ void k_prepW(const float* __restrict__ convW, float4* __restrict__ Wp) {
    int lane = threadIdx.x;  // 64
    int k = blockIdx.x;      // 64
    int l = blockIdx.y;      // 6
    const float* W1 = convW + ((size_t)l * 228 + k) * 128;
    const float* W2 = convW + ((size_t)l * 228 + 64 + k) * 128;
    Wp[((size_t)l * 64 + k) * 64 + lane] =
        make_float4(W1[lane], W1[lane + 64], W2[lane], W2[lane + 64]);
}

__global__ void k_embed(const int* __restrict__ an, const float* __restrict__ emb,
                        const float* __restrict__ W, const float* __restrict__ b,
                        float* __restrict__ x) {
    int c = threadIdx.x & 63, nl = threadIdx.x >> 6;
    int n = blockIdx.x * 4 + nl;
    if (n >= NN) return;
    const float* e = emb + (size_t)an[n] * 92;
    float acc = b[c];
#pragma unroll 4
    for (int k = 0; k < 92; k++) acc += e[k] * W[k * 64 + c];
    x[(size_t)n * 64 + c] = acc;
}

__global__ void k_hist(const int* __restrict__ dst, int* __restrict__ counts) {
    int e = blockIdx.x * 256 + threadIdx.x;
    if (e < EE) atomicAdd(&counts[dst[e]], 1);
}

__global__ void k_scan_local(const int* __restrict__ counts, int* __restrict__ rp,
                             int* __restrict__ bsum) {
    __shared__ int buf[1024];
    int b = blockIdx.x, tid = threadIdx.x;
    int i = b * 1024 + tid;
    int val = (i < NN) ? counts[i] : 0;
    buf[tid] = val;
    __syncthreads();
    for (int off = 1; off < 1024; off <<= 1) {
        int t = (tid >= off) ? buf[tid - off] : 0;
        __syncthreads();
        buf[tid] += t;
        __syncthreads();
    }
    if (i < NN) rp[i + 1] = buf[tid];
    if (tid == 1023) bsum[b] = buf[1023];
}

__global__ void k_scan_off(int* __restrict__ bsum, int nb) {
    if (threadIdx.x == 0) {
        int acc = 0;
        for (int b = 0; b < nb; b++) { int v = bsum[b]; bsum[b] = acc; acc += v; }
    }
}

__global__ void k_scan_add(int* __restrict__ rp, const int* __restrict__ bsum) {
    int b = blockIdx.x, tid = threadIdx.x;
    int i = b * 1024 + tid;
    if (i < NN) rp[i + 1] += bsum[b];
    if (b == 0 && tid == 0) rp[0] = 0;
}

// wave -> start node for edge-balanced k_stats (removes per-wave binary search)
__global__ void k_wsn(const int* __restrict__ rp, int* __restrict__ wsn) {
    int w = blockIdx.x * 256 + threadIdx.x;
    if (w >= SW) return;
    int e0 = (int)((long long)w * EE / SW);
    int lo = 0, hi = NN;
    while (lo + 1 < hi) {
        int mid = (lo + hi) >> 1;
        if (rp[mid] <= e0) lo = mid; else hi = mid;
    }
    wsn[w] = lo;
}

// scatter + pack fused: ej[pos] = (src<<13) | j  (dst-sorted order)
__global__ void k_scatter(const int* __restrict__ src, const int* __restrict__ dst,
                          const float* __restrict__ dist, const int* __restrict__ rp,
                          int* __restrict__ cursor, unsigned* __restrict__ ej) {
    int e = blockIdx.x * 256 + threadIdx.x;
    if (e < EE) {
        int d = dst[e];
        int p = atomicAdd(&cursor[d], 1);
        float t = dist[e] * ((TS - 1.0f) / 6.0f);
        int j = (int)(t + 0.5f);
        if (j > TS - 1) j = TS - 1;
        ej[rp[d] + p] = ((unsigned)src[e] << 13) | (unsigned)j;
    }
}

// u,v: 4 nodes per wave, Wp float4 loads, readlane broadcast
__global__ void __launch_bounds__(256) k_uv(const float* __restrict__ x,
                                            const float4* __restrict__ Wp,
                                            __half2* __restrict__ up, __half2* __restrict__ vp) {
    int lane = threadIdx.x & 63;
    int wv = __builtin_amdgcn_readfirstlane(threadIdx.x >> 6);
    int n0 = (blockIdx.x * 4 + wv) * 4;
    float xa = x[(size_t)(n0 + 0) * 64 + lane];
    float xb = x[(size_t)(n0 + 1) * 64 + lane];
    float xc = x[(size_t)(n0 + 2) * 64 + lane];
    float xd = x[(size_t)(n0 + 3) * 64 + lane];
    float2 ua = {0, 0}, ub = {0, 0}, uc = {0, 0}, ud = {0, 0};
    float2 va = {0, 0}, vb = {0, 0}, vc = {0, 0}, vd = {0, 0};
#pragma unroll 8
    for (int k = 0; k < 64; k++) {
        float4 w = Wp[k * 64 + lane];
        float ka = __uint_as_float(__builtin_amdgcn_readlane(__float_as_uint(xa), k));
        float kb = __uint_as_float(__builtin_amdgcn_readlane(__float_as_uint(xb), k));
        float kc = __uint_as_float(__builtin_amdgcn_readlane(__float_as_uint(xc), k));
        float kd = __uint_as_float(__builtin_amdgcn_readlane(__float_as_uint(xd), k));
        ua.x += ka * w.x; ua.y += ka * w.y; va.x += ka * w.z; va.y += ka * w.w;
        ub.x += kb * w.x; ub.y += kb * w.y; vb.x += kb * w.z; vb.y += kb * w.w;
        uc.x += kc * w.x; uc.y += kc * w.y; vc.x += kc * w.z; vc.y += kc * w.w;
        ud.x += kd * w.x; ud.y += kd * w.y; vd.x += kd * w.z; vd.y += kd * w.w;
    }
    up[(size_t)(n0 + 0) * 64 + lane] = __floats2half2_rn(ua.x, ua.y);
    up[(size_t)(n0 + 1) * 64 + lane] = __floats2half2_rn(ub.x, ub.y);
    up[(size_t)(n0 + 2) * 64 + lane] = __floats2half2_rn(uc.x, uc.y);
    up[(size_t)(n0 + 3) * 64 + lane] = __floats2half2_rn(ud.x, ud.y);
    vp[(size_t)(n0 + 0) * 64 + lane] = __floats2half2_rn(va.x, va.y);
    vp[(size_t)(n0 + 1) * 64 + lane] = __floats2half2_rn(vb.x, vb.y);
    vp[(size_t)(n0 + 2) * 64 + lane] = __floats2half2_rn(vc.x, vc.y);
    vp[(size_t)(n0 + 3) * 64 + lane] = __floats2half2_rn(vd.x, vd.y);
}

// Half-row gather group: lanes 0-31 = edge idx+2t, lanes 32-63 = edge idx+2t+1,
// each lane reads channel-pair hp = h*32 + (lane&31) (4B). 2 edges / instr,
// 128B per edge -> per-XCD working set halves (channel half pinned to XCD group).
#define GRP2(P, BODY)                                                        \
    {                                                                        \
        unsigned e[P];                                                       \
        _Pragma("unroll")                                                    \
        for (int t = 0; t < P; t++)                                          \
            e[t] = __builtin_nontemporal_load(&ej[idx + 2 * t + slot]);      \
        __half2 vh[P], th[P];                                                \
        _Pragma("unroll")                                                    \
        for (int t = 0; t < P; t++) {                                        \
            vh[t] = vp[(size_t)(e[t] >> 13) * 64 + hp];                      \
            th[t] = Tn[(size_t)(e[t] & 8191u) * 64 + hp];                    \
        }                                                                    \
        _Pragma("unroll")                                                    \
        for (int t = 0; t < P; t++) { BODY }                                 \
    }

#define STATS_BODY                                                           \
    float2 vv = __half22float2(vh[t]);                                       \
    float2 tt = __half22float2(th[t]);                                       \
    float z0 = uu.x + vv.x + tt.x;                                           \
    float z1 = uu.y + vv.y + tt.y;                                           \
    sx += z0; qx += z0 * z0; sy += z1; qy += z1 * z1;

#define AGG_BODY                                                             \
    float2 vv = __half22float2(vh[t]);                                       \
    float2 tt = __half22float2(th[t]);                                       \
    float z0 = (uu.x + vv.x + tt.x) * A1 + B1;                               \
    float z1 = (uu.y + vv.y + tt.y) * A2 + B2;                               \
    acc += sigmoid_fast(z0) * softplus_fast(z1);

// pass A: BN stats; channel-half h pinned to XCD group via blockIdx%8.
// 2048 blocks: h = (bid>>2)&1, per-half rank r = (bid>>3)*4 + (bid&3).
__global__ void __launch_bounds__(256) k_stats_h(
    const __half2* __restrict__ up, const __half2* __restrict__ vp,
    const __half2* __restrict__ Tn, const unsigned* __restrict__ ej,
    const int* __restrict__ rp, const int* __restrict__ wsn,
    float* __restrict__ sums) {
    int lane = threadIdx.x & 63;
    int wv = __builtin_amdgcn_readfirstlane(threadIdx.x >> 6);
    int bid = blockIdx.x;
    int h = (bid >> 2) & 1;
    int r = ((bid >> 3) << 2) | (bid & 3);
    int slot = lane >> 5;
    int hp = h * 32 + (lane & 31);
    int w = r * 4 + wv;
    int e0 = (int)((long long)w * EE / SW);
    int e1 = (int)((long long)(w + 1) * EE / SW);
    int n = __builtin_amdgcn_readfirstlane(wsn[w]);
    int rend = __builtin_amdgcn_readfirstlane(rp[n + 1]);
    float sx = 0.f, sy = 0.f, qx = 0.f, qy = 0.f;
    int idx = e0;
    while (idx < e1) {
        while (idx >= rend) {
            ++n;
            rend = __builtin_amdgcn_readfirstlane(rp[n + 1]);
        }
        float2 uu = __half22float2(up[(size_t)n * 64 + hp]);
        int stop = (e1 < rend) ? e1 : rend;
        for (; idx + 16 <= stop; idx += 16) GRP2(8, STATS_BODY)
        if (idx + 8 <= stop) { GRP2(4, STATS_BODY) idx += 8; }
        if (idx + 4 <= stop) { GRP2(2, STATS_BODY) idx += 4; }
        if (idx + 2 <= stop) { GRP2(1, STATS_BODY) idx += 2; }
        if (idx < stop) {  // odd tail: slot 0 only
            unsigned e = ej[idx];
            __half2 vh0 = vp[(size_t)(e >> 13) * 64 + hp];
            __half2 th0 = Tn[(size_t)(e & 8191u) * 64 + hp];
            float2 vv = __half22float2(vh0);
            float2 tt = __half22float2(th0);
            float z0 = uu.x + vv.x + tt.x;
            float z1 = uu.y + vv.y + tt.y;
            if (!slot) {
                sx += z0; qx += z0 * z0; sy += z1; qy += z1 * z1;
            }
            idx += 1;
        }
    }
    // combine edge slots (lanes l and l+32 hold same channels)
    sx += __shfl_xor(sx, 32, 64); sy += __shfl_xor(sy, 32, 64);
    qx += __shfl_xor(qx, 32, 64); qy += __shfl_xor(qy, 32, 64);
    __shared__ float red[4][32][4];
    if (!slot) {
        float* rr = red[wv][lane & 31];
        rr[0] = sx; rr[1] = sy; rr[2] = qx; rr[3] = qy;
    }
    __syncthreads();
    if (wv == 0 && !slot) {
        for (int q = 1; q < 4; q++) {
            const float* rr = red[q][lane & 31];
            sx += rr[0]; sy += rr[1]; qx += rr[2]; qy += rr[3];
        }
        int c0 = hp;  // z0 channel
        atomicAdd(&sums[c0], sx);
        atomicAdd(&sums[64 + c0], sy);
        atomicAdd(&sums[128 + c0], qx);
        atomicAdd(&sums[192 + c0], qy);
    }
}

// pass B: half-channel aggregate; writes partial acc (no LN here).
// 10000 blocks: h = (bid>>2)&1, per-half rank r = (bid>>3)*4 + (bid&3); node = r*4+wv.
__global__ void __launch_bounds__(256) k_aggh(
    const __half2* __restrict__ up, const __half2* __restrict__ vp,
    const __half2* __restrict__ Tn, const unsigned* __restrict__ ej,
    const int* __restrict__ rp, const float* __restrict__ sums,
    const float* __restrict__ bng, const float* __restrict__ bnb,
    int l, float* __restrict__ accbuf) {
    int lane = threadIdx.x & 63;
    int wv = __builtin_amdgcn_readfirstlane(threadIdx.x >> 6);
    int bid = blockIdx.x;
    int h = (bid >> 2) & 1;
    int r = ((bid >> 3) << 2) | (bid & 3);
    int slot = lane >> 5;
    int hp = h * 32 + (lane & 31);
    int i = r * 4 + wv;

    int c0 = hp;
    float mu1 = sums[c0] * (1.0f / EE);
    float var1 = sums[128 + c0] * (1.0f / EE) - mu1 * mu1;
    float A1 = rsqrtf(var1 + EPS) * bng[l * 128 + c0];
    float B1 = bnb[l * 128 + c0] - mu1 * A1;
    float mu2 = sums[64 + c0] * (1.0f / EE);
    float var2 = sums[192 + c0] * (1.0f / EE) - mu2 * mu2;
    float A2 = rsqrtf(var2 + EPS) * bng[l * 128 + 64 + c0];
    float B2 = bnb[l * 128 + 64 + c0] - mu2 * A2;

    float2 uu = __half22float2(up[(size_t)i * 64 + hp]);
    float acc = 0.f;
    int rs = __builtin_amdgcn_readfirstlane(rp[i]);
    int re = __builtin_amdgcn_readfirstlane(rp[i + 1]);
    int idx = rs;
    for (; idx + 16 <= re; idx += 16) GRP2(8, AGG_BODY)
    if (idx + 8 <= re) { GRP2(4, AGG_BODY) idx += 8; }
    if (idx + 4 <= re) { GRP2(2, AGG_BODY) idx += 4; }
    if (idx + 2 <= re) { GRP2(1, AGG_BODY) idx += 2; }
    if (idx < re) {  // odd tail: slot 0 only
        unsigned e = ej[idx];
        __half2 vh0 = vp[(size_t)(e >> 13) * 64 + hp];
        __half2 th0 = Tn[(size_t)(e & 8191u) * 64 + hp];
        float2 vv = __half22float2(vh0);
        float2 tt = __half22float2(th0);
        float z0 = (uu.x + vv.x + tt.x) * A1 + B1;
        float z1 = (uu.y + vv.y + tt.y) * A2 + B2;
        if (!slot) acc += sigmoid_fast(z0) * softplus_fast(z1);
    }
    acc += __shfl_xor(acc, 32, 64);
    if (!slot) accbuf[(size_t)i * 64 + hp] = acc;
}

// LN + residual + softplus epilogue (reads combined acc halves)
__global__ void __launch_bounds__(256) k_lnfin(
    const float* __restrict__ accbuf,
    const float* __restrict__ lng, const float* __restrict__ lnb,
    int l, const float* __restrict__ xin, float* __restrict__ xout) {
    int lane = threadIdx.x & 63;
    int wv = __builtin_amdgcn_readfirstlane(threadIdx.x >> 6);
    int i = blockIdx.x * 4 + wv;
    float a = accbuf[(size_t)i * 64 + lane];
    float xr = xin[(size_t)i * 64 + lane];
    float s = a;
#pragma unroll
    for (int off = 32; off; off >>= 1) s += __shfl_xor(s, off, 64);
    float mean = s * (1.0f / 64.0f);
    float e0v = a - mean;
    float vv2 = e0v * e0v;
#pragma unroll
    for (int off = 32; off; off >>= 1) vv2 += __shfl_xor(vv2, off, 64);
    float var = vv2 * (1.0f / 64.0f);
    float h = e0v * rsqrtf(var + EPS) * lng[l * 64 + lane] + lnb[l * 64 + lane];
    xout[(size_t)i * 64 + lane] = softplus_ref(h + xr);
}

// batch sorted -> graph row pointers by binary search
__global__ void k_gp(const int* __restrict__ batch, int* __restrict__ gp) {
    int g = threadIdx.x;
    if (g > GG) return;
    int lo = 0, hi = NN;
    while (lo < hi) {
        int mid = (lo + hi) >> 1;
        if (batch[mid] < g) lo = mid + 1; else hi = mid;
    }
    gp[g] = lo;
}

// atomic-free segmented mean-pool
__global__ void k_pool2(const float* __restrict__ x, const int* __restrict__ gp,
                        float* __restrict__ mols) {
    int g = blockIdx.x;
    int lane = threadIdx.x & 63, slot = threadIdx.x >> 6;
    int s0 = gp[g], s1 = gp[g + 1];
    float acc = 0.f;
    for (int n = s0 + slot; n < s1; n += 4) acc += x[(size_t)n * 64 + lane];
    __shared__ float red[4][64];
    red[slot][lane] = acc;
    __syncthreads();
    if (slot == 0) {
        float a = red[0][lane] + red[1][lane] + red[2][lane] + red[3][lane];
        float cc = fmaxf((float)(s1 - s0), 1.0f);
        mols[g * 64 + lane] = a / cc;
    }
}

__global__ void k_mlp(const float* __restrict__ mols,
                      const float* __restrict__ fc1W, const float* __restrict__ fc1b,
                      const float* __restrict__ fcsW, const float* __restrict__ fcsb,
                      const float* __restrict__ outW, const float* __restrict__ outb,
                      float* __restrict__ y) {
    int g = blockIdx.x, t = threadIdx.x; // 128 threads
    __shared__ float m[64];
    __shared__ float h[128];
    __shared__ float rbuf[128];
    if (t < 64) m[t] = mols[g * 64 + t];
    __syncthreads();
    float a = fc1b[t];
#pragma unroll 4
    for (int k = 0; k < 64; k++) a += m[k] * fc1W[k * 128 + t];
    h[t] = softplus_ref(a);
    __syncthreads();
    for (int i = 0; i < 3; i++) {
        float b = fcsb[i * 128 + t];
#pragma unroll 4
        for (int k = 0; k < 128; k++) b += h[k] * fcsW[((size_t)i * 128 + k) * 128 + t];
        __syncthreads();
        h[t] = softplus_ref(b);
        __syncthreads();
    }
    rbuf[t] = h[t] * outW[t];
    __syncthreads();
    if (t < 64) {
        float s2 = rbuf[t] + rbuf[t + 64];
#pragma unroll
        for (int off = 32; off; off >>= 1) s2 += __shfl_xor(s2, off, 64);
        if (t == 0) y[g] = s2 + outb[0];
    }
}

extern "C" void kernel_launch(void* const* d_in, const int* in_sizes, int n_in,
                              void* d_out, int out_size, void* d_ws, size_t ws_size,
                              hipStream_t stream) {
    const int*   an    = (const int*)d_in[0];
    const int*   nbr   = (const int*)d_in[1];
    const float* dist  = (const float*)d_in[2];
    const int*   batch = (const int*)d_in[3];
    const float* emb   = (const float*)d_in[4];
    const float* nucW  = (const float*)d_in[5];
    const float* nucB  = (const float*)d_in[6];
    const float* convW = (const float*)d_in[7];
    const float* convB = (const float*)d_in[8];
    const float* bng   = (const float*)d_in[9];
    const float* bnb   = (const float*)d_in[10];
    const float* lng   = (const float*)d_in[11];
    const float* lnb   = (const float*)d_in[12];
    const float* fc1W  = (const float*)d_in[13];
    const float* fc1b  = (const float*)d_in[14];
    const float* fcsW  = (const float*)d_in[15];
    const float* fcsb  = (const float*)d_in[16];
    const float* outW  = (const float*)d_in[17];
    const float* outb  = (const float*)d_in[18];
    const int* srcI = nbr;
    const int* dstI = nbr + EE;

    char* base = (char*)d_ws;
    size_t off = 0;
    auto alloc = [&](size_t b) { size_t r = off; off += (b + 255) & ~(size_t)255; return r; };
    float*    gtab   = (float*)(base + alloc((size_t)TS * 100 * 4));
    __half2*  Tall   = (__half2*)(base + alloc((size_t)6 * TS * 64 * 4));
    float4*   Wp     = (float4*)(base + alloc((size_t)6 * 64 * 64 * 16));
    float*    x0     = (float*)(base + alloc((size_t)NN * 64 * 4));
    float*    x1     = (float*)(base + alloc((size_t)NN * 64 * 4));
    __half2*  up     = (__half2*)(base + alloc((size_t)NN * 64 * 4));
    __half2*  vp     = (__half2*)(base + alloc((size_t)NN * 64 * 4));
    float*    accb   = (float*)(base + alloc((size_t)NN * 64 * 4));
    float*    sums6  = (float*)(base + alloc((size_t)6 * 256 * 4));
    int*      counts = (int*)(base + alloc((size_t)NN * 4));
    int*      cursor = (int*)(base + alloc((size_t)NN * 4));
    int*      rp     = (int*)(base + alloc((size_t)(NN + 1) * 4));
    int*      bsum   = (int*)(base + alloc(64 * 4));
    unsigned* ej     = (unsigned*)(base + alloc((size_t)(EE + 64) * 4));
    int*      wsn    = (int*)(base + alloc((size_t)SW * 4));
    float*    mols   = (float*)(base + alloc((size_t)GG * 64 * 4));
    int*      gp     = (int*)(base + alloc((size_t)(GG + 1) * 4));

    hipMemsetAsync(counts, 0, (size_t)NN * 4, stream);
    hipMemsetAsync(cursor, 0, (size_t)NN * 4, stream);
    hipMemsetAsync(sums6, 0, (size_t)6 * 256 * 4, stream);

    k_gtab<<<(TS * 100 + 255) / 256, 256, 0, stream>>>(gtab);
    k_build_T<<<dim3(TS / 16, 6), 256, 0, stream>>>(gtab, convW, convB, Tall);
    k_prepW<<<dim3(64, 6), 64, 0, stream>>>(convW, Wp);
    k_embed<<<(NN + 3) / 4, 256, 0, stream>>>(an, emb, nucW, nucB, x0);
    k_hist<<<(EE + 255) / 256, 256, 0, stream>>>(dstI, counts);
    const int NB = (NN + 1023) / 1024;
    k_scan_local<<<NB, 1024, 0, stream>>>(counts, rp, bsum);
    k_scan_off<<<1, 64, 0, stream>>>(bsum, NB);
    k_scan_add<<<NB, 1024, 0, stream>>>(rp, bsum);
    k_wsn<<<SW / 256, 256, 0, stream>>>(rp, wsn);
    k_scatter<<<(EE + 255) / 256, 256, 0, stream>>>(srcI, dstI, dist, rp, cursor, ej);
    k_gp<<<1, 128, 0, stream>>>(batch, gp);

    float* xin = x0;
    float* xout = x1;
    for (int l = 0; l < 6; l++) {
        k_uv<<<NN / 16, 256, 0, stream>>>(xin, Wp + (size_t)l * 64 * 64, up, vp);
        const __half2* Tnl = Tall + (size_t)l * TS * 64;
        float* sums = sums6 + (size_t)l * 256;
        k_stats_h<<<2048, 256, 0, stream>>>(up, vp, Tnl, ej, rp, wsn, sums);
        k_aggh<<<10000, 256, 0, stream>>>(up, vp, Tnl, ej, rp, sums,
                                          bng, bnb, l, accb);
        k_lnfin<<<NN / 4, 256, 0, stream>>>(accb, lng, lnb, l, xin, xout);
        float* tmp = xin; xin = xout; xout = tmp;
    }
    k_pool2<<<GG, 256, 0, stream>>>(xin, gp, mols);
    k_mlp<<<GG, 128, 0, stream>>>(mols, fc1W, fc1b, fcsW, fcsb, outW, outb, (float*)d_out);
}